// Round 2
// baseline (833.141 us; speedup 1.0000x reference)
//
#include <hip/hip_runtime.h>

typedef unsigned short u16;
typedef __attribute__((ext_vector_type(8))) __bf16 bf16x8;
typedef __attribute__((ext_vector_type(16))) float f32x16;

__device__ __forceinline__ float bf2f(u16 u) {
  union { unsigned i; float f; } x; x.i = ((unsigned)u) << 16; return x.f;
}
__device__ __forceinline__ u16 f2bf(float f) {
  union { float f; unsigned i; } x; x.f = f;
  unsigned r = x.i + 0x7FFFu + ((x.i >> 16) & 1u);
  return (u16)(r >> 16);
}
__device__ __forceinline__ bf16x8 ld8(const u16* p) {
  union { int2 i2[2]; bf16x8 v; } u;
  u.i2[0] = *(const int2*)p;
  u.i2[1] = *(const int2*)(p + 4);
  return u.v;
}

// ---------------- weight transform: f32 w[Cout][Cin][kh][kw] -> bf16 wT[Cout_pad][taps*Ck] ----------------
struct WJob { const float* src; u16* dst; int Cin, Cout, taps, Ck, Cpad; };
struct WArgs {
  WJob j[18];
  const float *cls_b, *box_b, *ctr_b;
  float *bcls, *bbc;
};

__global__ __launch_bounds__(256) void wtrans_kernel(WArgs a) {
  WJob jb = a.j[blockIdx.y];
  int Kpad = jb.taps * jb.Ck;
  int count = jb.Cpad * Kpad;
  for (int e = blockIdx.x * 256 + threadIdx.x; e < count; e += gridDim.x * 256) {
    int co = e / Kpad;
    int k = e - co * Kpad;
    int tap = k / jb.Ck;
    int ci = k - tap * jb.Ck;
    float v = 0.f;
    if (co < jb.Cout && ci < jb.Cin)
      v = jb.src[(size_t)(co * jb.Cin + ci) * jb.taps + tap];
    jb.dst[e] = f2bf(v);
  }
  if (blockIdx.y == 0 && blockIdx.x == 0) {
    int t = threadIdx.x;
    if (t < 128) a.bcls[t] = (t < 80) ? a.cls_b[t] : 0.f;
    else if (t < 192) {
      int n = t - 128;
      a.bbc[n] = (n < 4) ? a.box_b[n] : (n == 4 ? a.ctr_b[0] : 0.f);
    }
  }
}

// ---------------- f32 NCHW -> bf16 NHWC ----------------
__global__ __launch_bounds__(256) void transpose_kernel(const float* __restrict__ in,
                                                        u16* __restrict__ out,
                                                        int C, int HW, int total) {
  int gid = blockIdx.x * 256 + threadIdx.x;
  if (gid >= total) return;
  int CHW = C * HW;
  int b = gid / CHW;
  int rem = gid - b * CHW;
  int c = rem / HW;
  int pos = rem - c * HW;
  out[((size_t)b * HW + pos) * C + c] = f2bf(in[gid]);
}

// ---------------- dst(B,H,W,256) += nearest-up2x(src(B,H/2,W/2,256)), bf16 internal ----------------
__global__ __launch_bounds__(256) void upadd_kernel(u16* __restrict__ dst, const u16* __restrict__ src,
                                                    int lgW, int lgHW, int total) {
  int gid = blockIdx.x * 256 + threadIdx.x;
  if (gid >= total) return;
  int c = gid & 255;
  int m = gid >> 8;
  int HW = 1 << lgHW, W = 1 << lgW;
  int b = m >> lgHW;
  int pos = m & (HW - 1);
  int y = pos >> lgW, x = pos & (W - 1);
  int sp = (b << (lgHW - 2)) + ((y >> 1) << (lgW - 1)) + (x >> 1);
  dst[gid] = f2bf(bf2f(dst[gid]) + bf2f(src[(size_t)sp * 256 + c]));
}

// ---------------- implicit-GEMM conv via mfma_f32_32x32x16_bf16 ----------------
// block = 256 threads (4 waves); tile BM=128 (wave w: rows w*32..w*32+31), BN=64 (2 n-frags of 32).
// LDS tiles row-stride 68 shorts (136B): 2-way-only bank aliasing on b64 frag reads (free).
struct ConvP {
  const u16* src[2][3];
  const u16* wT[2][3];
  const float* bias[2][3];
  void* dst[2][3];
  int H[3], W[3], HW[3], lgW[3], lgHW[3], pre[3], Ck[3], Crow[3], locoff[3];
  int taps, relu, direct, Nvalid, choff, CoutRow;
};

#define LDA 68

__global__ __launch_bounds__(256, 2) void conv_kernel(ConvP p) {
  __shared__ u16 As[128 * LDA];
  __shared__ u16 Bs[64 * LDA];
  const int tid = threadIdx.x;
  const int bx = blockIdx.x;
  const int lv = (bx >= p.pre[1]) + (bx >= p.pre[2]);
  const int br = blockIdx.z;
  const u16* __restrict__ src = p.src[br][lv];
  const u16* __restrict__ wT = p.wT[br][lv];
  const float* bias = p.bias[br][lv];
  void* dstv = p.dst[br][lv];
  const int H = p.H[lv], W = p.W[lv], HW = p.HW[lv];
  const int lgWv = p.lgW[lv], lgHWv = p.lgHW[lv];
  const int Ck = p.Ck[lv], Crow = p.Crow[lv];
  const int Kpad = p.taps * Ck;
  const int mt = (bx - p.pre[lv]) * 128;
  const int nt = blockIdx.y * 64;
  const int wave = tid >> 6, lane = tid & 63;
  const int batch = mt >> lgHWv;          // tile never straddles batch (HW % 128 == 0)
  const int posbase = mt & (HW - 1);
  const size_t srcb = (size_t)batch * HW * Crow;

  f32x16 acc[2];
#pragma unroll
  for (int i = 0; i < 16; ++i) { acc[0][i] = 0.f; acc[1][i] = 0.f; }

  const int nchunks = (p.taps == 9) ? 36 : (Ck >> 6);
  const int sr = tid >> 3;          // 0..31
  const int sc = (tid & 7) * 8;     // 0..56

  for (int cc = 0; cc < nchunks; ++cc) {
    int tap, kc;
    if (p.taps == 9) { tap = cc >> 2; kc = (cc & 3) << 6; }
    else             { tap = 0;       kc = cc << 6; }
    int dy = 0, dx = 0;
    if (p.taps == 9) { int t3 = tap / 3; dy = t3 - 1; dx = tap - t3 * 3 - 1; }
    const int kb = tap * Ck + kc;

    __syncthreads();
    // stage A: 128 rows x 64 k (zero-padded at image borders / beyond Crow)
#pragma unroll
    for (int pp = 0; pp < 4; ++pp) {
      int r = pp * 32 + sr;
      int pos = posbase + r;
      int y = pos >> lgWv, x = pos & (W - 1);
      int ys = y + dy, xs = x + dx;
      int4 v = make_int4(0, 0, 0, 0);
      if ((unsigned)ys < (unsigned)H && (unsigned)xs < (unsigned)W && (kc + sc) < Crow) {
        v = *(const int4*)(src + srcb + ((size_t)(ys << lgWv) + xs) * Crow + kc + sc);
      }
      u16* d = &As[r * LDA + sc];
      *(int2*)d = make_int2(v.x, v.y);
      *(int2*)(d + 4) = make_int2(v.z, v.w);
    }
    // stage B: 64 rows (n) x 64 k
#pragma unroll
    for (int pp = 0; pp < 2; ++pp) {
      int r = pp * 32 + sr;
      int4 v = *(const int4*)(wT + (size_t)(nt + r) * Kpad + kb + sc);
      u16* d = &Bs[r * LDA + sc];
      *(int2*)d = make_int2(v.x, v.y);
      *(int2*)(d + 4) = make_int2(v.z, v.w);
    }
    __syncthreads();

    const u16* arow = &As[(wave * 32 + (lane & 31)) * LDA + ((lane >> 5) * 8)];
    const u16* brow0 = &Bs[(lane & 31) * LDA + ((lane >> 5) * 8)];
    const u16* brow1 = brow0 + 32 * LDA;
#pragma unroll
    for (int ks = 0; ks < 4; ++ks) {
      bf16x8 af = ld8(arow + ks * 16);
      bf16x8 bf0 = ld8(brow0 + ks * 16);
      bf16x8 bf1 = ld8(brow1 + ks * 16);
      acc[0] = __builtin_amdgcn_mfma_f32_32x32x16_bf16(af, bf0, acc[0], 0, 0, 0);
      acc[1] = __builtin_amdgcn_mfma_f32_32x32x16_bf16(af, bf1, acc[1], 0, 0, 0);
    }
  }

  // epilogue: C/D layout col=lane&31, row=(reg&3)+8*(reg>>2)+4*(lane>>5)
  const int col = lane & 31;
  const int rb = 4 * (lane >> 5);
#pragma unroll
  for (int nf = 0; nf < 2; ++nf) {
    int n = nt + nf * 32 + col;
    float bv = bias[n];
#pragma unroll
    for (int r = 0; r < 16; ++r) {
      int mloc = wave * 32 + rb + (r & 3) + 8 * (r >> 2);
      float v = acc[nf][r] + bv;
      if (p.relu) v = fmaxf(v, 0.f);
      if (!p.direct) {
        ((u16*)dstv)[(size_t)(mt + mloc) * p.CoutRow + n] = f2bf(v);
      } else {
        if (n < p.Nvalid) {
          int pos = posbase + mloc;
          ((float*)dstv)[((size_t)(batch * 5376 + p.locoff[lv] + pos)) * 85 + p.choff + n] = v;
        }
      }
    }
  }
}

// ---------------- host ----------------
extern "C" void kernel_launch(void* const* d_in, const int* in_sizes, int n_in,
                              void* d_out, int out_size, void* d_ws, size_t ws_size,
                              hipStream_t stream) {
  (void)in_sizes; (void)n_in; (void)out_size; (void)ws_size;
  const float* c3 = (const float*)d_in[0];
  const float* c4 = (const float*)d_in[1];
  const float* c5 = (const float*)d_in[2];
  const float* lat_w[3] = {(const float*)d_in[3], (const float*)d_in[7], (const float*)d_in[11]};
  const float* lat_b[3] = {(const float*)d_in[4], (const float*)d_in[8], (const float*)d_in[12]};
  const float* out_w[3] = {(const float*)d_in[5], (const float*)d_in[9], (const float*)d_in[13]};
  const float* out_b[3] = {(const float*)d_in[6], (const float*)d_in[10], (const float*)d_in[14]};
  const float* scw = (const float*)d_in[15];
  const float* scb = (const float*)d_in[16];
  const float* sbw = (const float*)d_in[17];
  const float* sbb = (const float*)d_in[18];
  const float* clsw = (const float*)d_in[19];
  const float* clsb = (const float*)d_in[20];
  const float* boxw = (const float*)d_in[21];
  const float* boxb = (const float*)d_in[22];
  const float* ctrw = (const float*)d_in[23];
  const float* ctrb = (const float*)d_in[24];
  float* out = (float*)d_out;
  u16* ws = (u16*)d_ws;

  size_t o = 0;
  auto alloc = [&](size_t n) { size_t r = o; o += (n + 127) & ~(size_t)127; return ws + r; };

  u16* c3t = alloc(524288);
  u16* c4t = alloc(327680);
  u16* c5t = alloc(204800);
  u16* l3 = alloc(2097152);
  u16* l4 = alloc(524288);
  u16* l5 = alloc(131072);
  u16* p3 = alloc(2097152);
  u16* p4 = alloc(524288);
  u16* p5 = alloc(131072);
  const size_t hsz[3] = {2097152, 524288, 131072};
  u16 *hc[2][3], *hb[2][3];
  for (int ab = 0; ab < 2; ++ab)
    for (int lvv = 0; lvv < 3; ++lvv) { hc[ab][lvv] = alloc(hsz[lvv]); hb[ab][lvv] = alloc(hsz[lvv]); }
  const int latCin[3] = {64, 160, 400};
  const int latCk[3] = {64, 192, 448};
  u16* wl[3]; for (int i = 0; i < 3; ++i) wl[i] = alloc((size_t)256 * latCk[i]);
  u16* wo[3]; for (int i = 0; i < 3; ++i) wo[i] = alloc(589824);
  u16* wsc[4]; for (int i = 0; i < 4; ++i) wsc[i] = alloc(589824);
  u16* wsb[4]; for (int i = 0; i < 4; ++i) wsb[i] = alloc(589824);
  u16* wcls = alloc(294912);
  u16* wbc = alloc(147456);
  float* bcls = (float*)alloc(256);
  float* bbc = (float*)alloc(128);

  // ---- weight transforms ----
  WArgs wa;
  int ji = 0;
  for (int i = 0; i < 3; ++i) wa.j[ji++] = WJob{lat_w[i], wl[i], latCin[i], 256, 1, latCk[i], 256};
  for (int i = 0; i < 3; ++i) wa.j[ji++] = WJob{out_w[i], wo[i], 256, 256, 9, 256, 256};
  for (int i = 0; i < 4; ++i) wa.j[ji++] = WJob{scw + (size_t)i * 589824, wsc[i], 256, 256, 9, 256, 256};
  for (int i = 0; i < 4; ++i) wa.j[ji++] = WJob{sbw + (size_t)i * 589824, wsb[i], 256, 256, 9, 256, 256};
  wa.j[ji++] = WJob{clsw, wcls, 256, 80, 9, 256, 128};
  wa.j[ji++] = WJob{boxw, wbc, 256, 4, 9, 256, 4};
  wa.j[ji++] = WJob{ctrw, wbc + (size_t)4 * 2304, 256, 1, 9, 256, 1};
  wa.j[ji++] = WJob{nullptr, wbc + (size_t)5 * 2304, 0, 0, 9, 256, 59};
  wa.cls_b = clsb; wa.box_b = boxb; wa.ctr_b = ctrb; wa.bcls = bcls; wa.bbc = bbc;
  wtrans_kernel<<<dim3(64, 18), dim3(256), 0, stream>>>(wa);

  // ---- f32 NCHW -> bf16 NHWC ----
  transpose_kernel<<<dim3(2048), dim3(256), 0, stream>>>(c3, c3t, 64, 4096, 524288);
  transpose_kernel<<<dim3(1280), dim3(256), 0, stream>>>(c4, c4t, 160, 1024, 327680);
  transpose_kernel<<<dim3(800), dim3(256), 0, stream>>>(c5, c5t, 400, 256, 204800);

  const int Hs[3] = {64, 32, 16}, HWs[3] = {4096, 1024, 256};
  const int lgWs[3] = {6, 5, 4}, lgHWs[3] = {12, 10, 8};
  const int mt3[3] = {64, 16, 4};

  // ---- lateral 1x1 convs (all levels fused) ----
  {
    ConvP p{};
    const u16* srcs[3] = {c3t, c4t, c5t};
    u16* dsts[3] = {l3, l4, l5};
    for (int i = 0; i < 3; ++i) {
      p.src[0][i] = srcs[i]; p.wT[0][i] = wl[i]; p.bias[0][i] = lat_b[i]; p.dst[0][i] = dsts[i];
      p.H[i] = Hs[i]; p.W[i] = Hs[i]; p.HW[i] = HWs[i]; p.lgW[i] = lgWs[i]; p.lgHW[i] = lgHWs[i];
      p.Ck[i] = latCk[i]; p.Crow[i] = latCin[i]; p.locoff[i] = 0;
    }
    p.pre[0] = 0; p.pre[1] = 64; p.pre[2] = 80;
    p.taps = 1; p.relu = 0; p.direct = 0; p.Nvalid = 0; p.choff = 0; p.CoutRow = 256;
    conv_kernel<<<dim3(84, 4, 1), dim3(256), 0, stream>>>(p);
  }

  // ---- FPN top-down ----
  auto out_conv = [&](int lvv, const u16* s, u16* dd) {
    ConvP p{};
    p.src[0][0] = s; p.wT[0][0] = wo[lvv]; p.bias[0][0] = out_b[lvv]; p.dst[0][0] = dd;
    p.H[0] = Hs[lvv]; p.W[0] = Hs[lvv]; p.HW[0] = HWs[lvv]; p.lgW[0] = lgWs[lvv]; p.lgHW[0] = lgHWs[lvv];
    p.Ck[0] = 256; p.Crow[0] = 256; p.locoff[0] = 0;
    p.pre[0] = 0; p.pre[1] = 0x7fffffff; p.pre[2] = 0x7fffffff;
    p.taps = 9; p.relu = 0; p.direct = 0; p.Nvalid = 0; p.choff = 0; p.CoutRow = 256;
    conv_kernel<<<dim3(mt3[lvv], 4, 1), dim3(256), 0, stream>>>(p);
  };
  out_conv(2, l5, p5);
  upadd_kernel<<<dim3(2048), dim3(256), 0, stream>>>(l4, l5, 5, 10, 524288);
  out_conv(1, l4, p4);
  upadd_kernel<<<dim3(8192), dim3(256), 0, stream>>>(l3, l4, 6, 12, 2097152);
  out_conv(0, l3, p3);

  // ---- stem layers: all levels + both branches fused per layer ----
  u16* pin[3] = {p3, p4, p5};
  for (int i = 0; i < 4; ++i) {
    ConvP p{};
    int di = i & 1;
    for (int lvv = 0; lvv < 3; ++lvv) {
      const u16 *s0, *s1;
      if (i == 0) { s0 = pin[lvv]; s1 = pin[lvv]; }
      else { int si = (i - 1) & 1; s0 = hc[si][lvv]; s1 = hb[si][lvv]; }
      p.src[0][lvv] = s0; p.src[1][lvv] = s1;
      p.wT[0][lvv] = wsc[i]; p.wT[1][lvv] = wsb[i];
      p.bias[0][lvv] = scb + i * 256; p.bias[1][lvv] = sbb + i * 256;
      p.dst[0][lvv] = hc[di][lvv]; p.dst[1][lvv] = hb[di][lvv];
      p.H[lvv] = Hs[lvv]; p.W[lvv] = Hs[lvv]; p.HW[lvv] = HWs[lvv];
      p.lgW[lvv] = lgWs[lvv]; p.lgHW[lvv] = lgHWs[lvv];
      p.Ck[lvv] = 256; p.Crow[lvv] = 256; p.locoff[lvv] = 0;
    }
    p.pre[0] = 0; p.pre[1] = 64; p.pre[2] = 80;
    p.taps = 9; p.relu = 1; p.direct = 0; p.Nvalid = 0; p.choff = 0; p.CoutRow = 256;
    conv_kernel<<<dim3(84, 4, 2), dim3(256), 0, stream>>>(p);
  }

  // ---- final cls / box+ctr convs, writing straight into f32 (B,5376,85) output ----
  const int locoffs[3] = {0, 4096, 5120};
  {
    ConvP p{};
    for (int lvv = 0; lvv < 3; ++lvv) {
      p.src[0][lvv] = hc[1][lvv]; p.wT[0][lvv] = wcls; p.bias[0][lvv] = bcls; p.dst[0][lvv] = out;
      p.H[lvv] = Hs[lvv]; p.W[lvv] = Hs[lvv]; p.HW[lvv] = HWs[lvv];
      p.lgW[lvv] = lgWs[lvv]; p.lgHW[lvv] = lgHWs[lvv];
      p.Ck[lvv] = 256; p.Crow[lvv] = 256; p.locoff[lvv] = locoffs[lvv];
    }
    p.pre[0] = 0; p.pre[1] = 64; p.pre[2] = 80;
    p.taps = 9; p.relu = 0; p.direct = 1; p.Nvalid = 80; p.choff = 0; p.CoutRow = 256;
    conv_kernel<<<dim3(84, 2, 1), dim3(256), 0, stream>>>(p);
  }
  {
    ConvP p{};
    for (int lvv = 0; lvv < 3; ++lvv) {
      p.src[0][lvv] = hb[1][lvv]; p.wT[0][lvv] = wbc; p.bias[0][lvv] = bbc; p.dst[0][lvv] = out;
      p.H[lvv] = Hs[lvv]; p.W[lvv] = Hs[lvv]; p.HW[lvv] = HWs[lvv];
      p.lgW[lvv] = lgWs[lvv]; p.lgHW[lvv] = lgHWs[lvv];
      p.Ck[lvv] = 256; p.Crow[lvv] = 256; p.locoff[lvv] = locoffs[lvv];
    }
    p.pre[0] = 0; p.pre[1] = 64; p.pre[2] = 80;
    p.taps = 9; p.relu = 0; p.direct = 1; p.Nvalid = 5; p.choff = 80; p.CoutRow = 256;
    conv_kernel<<<dim3(84, 1, 1), dim3(256), 0, stream>>>(p);
  }
}

// Round 3
// 550.273 us; speedup vs baseline: 1.5141x; 1.5141x over previous
//
#include <hip/hip_runtime.h>

typedef unsigned short u16;
typedef __attribute__((ext_vector_type(8))) __bf16 bf16x8;
typedef __attribute__((ext_vector_type(16))) float f32x16;

__device__ __forceinline__ float bf2f(u16 u) {
  union { unsigned i; float f; } x; x.i = ((unsigned)u) << 16; return x.f;
}
__device__ __forceinline__ u16 f2bf(float f) {
  union { float f; unsigned i; } x; x.f = f;
  unsigned r = x.i + 0x7FFFu + ((x.i >> 16) & 1u);
  return (u16)(r >> 16);
}
__device__ __forceinline__ bf16x8 ld8(const u16* p) {
  union { int2 i2[2]; bf16x8 v; } u;
  u.i2[0] = *(const int2*)p;
  u.i2[1] = *(const int2*)(p + 4);
  return u.v;
}

// ---------------- weight transform ----------------
// f32 w[Cout][Cin][3][3] -> bf16 wT[tap][cc][n][64]  (cc = 64-ch chunk, zero-padded)
struct WJob { const float* src; u16* dst; int Cin, Cout, taps, NC, Cpad, special; };
struct WArgs {
  WJob j[16];
  const float *box_w, *ctr_w;
  const float *cls_b, *box_b, *ctr_b;
  float *bcls, *bbc;
};

__global__ __launch_bounds__(256) void wtrans_kernel(WArgs a) {
  WJob jb = a.j[blockIdx.y];
  int count = jb.taps * jb.NC * jb.Cpad * 64;
  for (int e = blockIdx.x * 256 + threadIdx.x; e < count; e += gridDim.x * 256) {
    int cw = e & 63;
    int r = e >> 6;
    int n = r % jb.Cpad;
    int q = r / jb.Cpad;
    int cc = q % jb.NC;
    int t = q / jb.NC;
    int ci = cc * 64 + cw;
    float v = 0.f;
    if (jb.special) {
      if (ci < jb.Cin) {
        if (n < 4) v = a.box_w[((size_t)n * jb.Cin + ci) * jb.taps + t];
        else if (n == 4) v = a.ctr_w[(size_t)ci * jb.taps + t];
      }
    } else if (n < jb.Cout && ci < jb.Cin) {
      v = jb.src[((size_t)n * jb.Cin + ci) * jb.taps + t];
    }
    jb.dst[e] = f2bf(v);
  }
  if (blockIdx.y == 0 && blockIdx.x == 0) {
    int t = threadIdx.x;
    if (t < 128) a.bcls[t] = (t < 80) ? a.cls_b[t] : 0.f;
    else if (t < 192) {
      int n = t - 128;
      a.bbc[n] = (n < 4) ? a.box_b[n] : (n == 4 ? a.ctr_b[0] : 0.f);
    }
  }
}

// ---------------- f32 NCHW -> bf16 NHWC ----------------
__global__ __launch_bounds__(256) void transpose_kernel(const float* __restrict__ in,
                                                        u16* __restrict__ out,
                                                        int C, int HW, int total) {
  int gid = blockIdx.x * 256 + threadIdx.x;
  if (gid >= total) return;
  int CHW = C * HW;
  int b = gid / CHW;
  int rem = gid - b * CHW;
  int c = rem / HW;
  int pos = rem - c * HW;
  out[((size_t)b * HW + pos) * C + c] = f2bf(in[gid]);
}

// ---------------- dst(B,H,W,256) += nearest-up2x(src(B,H/2,W/2,256)) ----------------
__global__ __launch_bounds__(256) void upadd_kernel(u16* __restrict__ dst, const u16* __restrict__ src,
                                                    int lgW, int lgHW, int total) {
  int gid = blockIdx.x * 256 + threadIdx.x;
  if (gid >= total) return;
  int c = gid & 255;
  int m = gid >> 8;
  int HW = 1 << lgHW, W = 1 << lgW;
  int b = m >> lgHW;
  int pos = m & (HW - 1);
  int y = pos >> lgW, x = pos & (W - 1);
  int sp = (b << (lgHW - 2)) + ((y >> 1) << (lgW - 1)) + (x >> 1);
  dst[gid] = f2bf(bf2f(dst[gid]) + bf2f(src[(size_t)sp * 256 + c]));
}

// ---------------- halo implicit-GEMM conv via mfma_f32_32x32x16_bf16 ----------------
// BM=128, BN=64. A-halo staged once per 64-ch chunk; B (8.5 KB/tap) double-buffered,
// prefetched during previous tap's compute -> 1 barrier per tap.
struct ConvP {
  const u16* src[2][3];
  const u16* wT[2][3];
  const float* bias[2][3];
  void* dst[2][3];
  int H[3], W[3], lgW[3], lgHW[3], pre[3], NC[3], Crow[3], locoff[3], haloW[3], nA8[3];
  int taps, relu, direct, Nvalid, choff, CoutRow, Cpad;
};

#define APAD 68

__global__ __launch_bounds__(256, 3) void conv_kernel(ConvP p) {
  __shared__ u16 As[264 * APAD];      // 35.9 KB
  __shared__ u16 Bs[2][64 * APAD];    // 17.4 KB  (total 53.3 KB -> 3 blocks/CU)
  const int tid = threadIdx.x;
  const int bx = blockIdx.x;
  const int lv = (bx >= p.pre[1]) + (bx >= p.pre[2]);
  const int br = blockIdx.z;
  const u16* __restrict__ src = p.src[br][lv];
  const u16* __restrict__ wT = p.wT[br][lv];
  const float* bias = p.bias[br][lv];
  void* dstv = p.dst[br][lv];
  const int H = p.H[lv], W = p.W[lv];
  const int lgWv = p.lgW[lv], lgHWv = p.lgHW[lv];
  const int HW = 1 << lgHWv;
  const int NCv = p.NC[lv], Crow = p.Crow[lv];
  const int haloWv = p.haloW[lv], nA8 = p.nA8[lv];
  const int taps = p.taps;
  const int off = (taps == 9) ? 1 : 0;
  const int mt = (bx - p.pre[lv]) * 128;
  const int nt = blockIdx.y * 64;
  const int wave = tid >> 6, lane = tid & 63;
  const int batch = mt >> lgHWv;            // tiles never straddle batch (128 | HW)
  const int posbase = mt & (HW - 1);
  const int ty0 = posbase >> lgWv;
  const size_t srcb = (size_t)batch * HW * Crow;

  f32x16 acc[2];
#pragma unroll
  for (int i = 0; i < 16; ++i) { acc[0][i] = 0.f; acc[1][i] = 0.f; }

  const int mloc = wave * 32 + (lane & 31);
  const int ty = mloc >> lgWv, tx = mloc & (W - 1);
  const int koff = (lane >> 5) << 3;

  auto stageA = [&](int cc2) {
    int kb = cc2 << 6;
    for (int idx = tid; idx < nA8; idx += 256) {
      int pos = idx >> 3, part = idx & 7;
      int hy = pos / haloWv;
      int hx = pos - hy * haloWv;
      int gy = ty0 + hy - off, gx = hx - off;
      int ch = kb + (part << 3);
      int4 v = make_int4(0, 0, 0, 0);
      if ((unsigned)gy < (unsigned)H && (unsigned)gx < (unsigned)W && ch < Crow)
        v = *(const int4*)(src + srcb + (size_t)((gy << lgWv) + gx) * Crow + ch);
      u16* d = &As[pos * APAD + (part << 3)];
      *(int2*)d = make_int2(v.x, v.y);
      *(int2*)(d + 4) = make_int2(v.z, v.w);
    }
  };

  auto stageB = [&](int cc2, int t2, int bufi) {
    const u16* wsrc = wT + (((size_t)(t2 * NCv + cc2) * p.Cpad + nt) << 6);
    u16* bb = &Bs[bufi][0];
#pragma unroll
    for (int pp = 0; pp < 2; ++pp) {
      int idx = pp * 256 + tid;
      int row = idx >> 3, part = idx & 7;
      int4 v = *(const int4*)(wsrc + (row << 6) + (part << 3));
      u16* d = &bb[row * APAD + (part << 3)];
      *(int2*)d = make_int2(v.x, v.y);
      *(int2*)(d + 4) = make_int2(v.z, v.w);
    }
  };

  auto computeTap = [&](int t2, int bufi) {
    int dy = 0, dx = 0;
    if (taps == 9) { int t3 = t2 / 3; dy = t3 - 1; dx = t2 - t3 * 3 - 1; }
    int hp = (ty + dy + off) * haloWv + (tx + dx + off);
    const u16* ar = &As[hp * APAD + koff];
    const u16* br0 = &Bs[bufi][(lane & 31) * APAD + koff];
#pragma unroll
    for (int ks = 0; ks < 4; ++ks) {
      bf16x8 af = ld8(ar + ks * 16);
      bf16x8 b0 = ld8(br0 + ks * 16);
      bf16x8 b1 = ld8(br0 + 32 * APAD + ks * 16);
      acc[0] = __builtin_amdgcn_mfma_f32_32x32x16_bf16(af, b0, acc[0], 0, 0, 0);
      acc[1] = __builtin_amdgcn_mfma_f32_32x32x16_bf16(af, b1, acc[1], 0, 0, 0);
    }
  };

  int kk = 0;
  const int ktot = NCv * taps;
  stageB(0, 0, 0);
  for (int cc = 0; cc < NCv; ++cc) {
    __syncthreads();            // prev chunk's computes done -> As/B safe
    stageA(cc);
    __syncthreads();            // As + pre-staged B visible
    for (int t = 0; t < taps; ++t) {
      int kn = kk + 1;
      if (kn < ktot) {
        int ncc = cc, ntp = t + 1;
        if (ntp == taps) { ncc = cc + 1; ntp = 0; }
        stageB(ncc, ntp, kn & 1);
      }
      computeTap(t, kk & 1);
      ++kk;
      if (t != taps - 1) __syncthreads();
    }
  }

  // epilogue: C/D layout col=lane&31, row=(reg&3)+8*(reg>>2)+4*(lane>>5)
  const int col = lane & 31;
  const int rb = 4 * (lane >> 5);
#pragma unroll
  for (int nf = 0; nf < 2; ++nf) {
    int n = nt + nf * 32 + col;
    float bv = bias[n];
#pragma unroll
    for (int r = 0; r < 16; ++r) {
      int ml = wave * 32 + rb + (r & 3) + 8 * (r >> 2);
      float v = acc[nf][r] + bv;
      if (p.relu) v = fmaxf(v, 0.f);
      if (!p.direct) {
        ((u16*)dstv)[(size_t)(mt + ml) * p.CoutRow + n] = f2bf(v);
      } else {
        if (n < p.Nvalid) {
          int pos = posbase + ml;
          ((float*)dstv)[((size_t)(batch * 5376 + p.locoff[lv] + pos)) * 85 + p.choff + n] = v;
        }
      }
    }
  }
}

// ---------------- host ----------------
extern "C" void kernel_launch(void* const* d_in, const int* in_sizes, int n_in,
                              void* d_out, int out_size, void* d_ws, size_t ws_size,
                              hipStream_t stream) {
  (void)in_sizes; (void)n_in; (void)out_size; (void)ws_size;
  const float* c3 = (const float*)d_in[0];
  const float* c4 = (const float*)d_in[1];
  const float* c5 = (const float*)d_in[2];
  const float* lat_w[3] = {(const float*)d_in[3], (const float*)d_in[7], (const float*)d_in[11]};
  const float* lat_b[3] = {(const float*)d_in[4], (const float*)d_in[8], (const float*)d_in[12]};
  const float* out_w[3] = {(const float*)d_in[5], (const float*)d_in[9], (const float*)d_in[13]};
  const float* out_b[3] = {(const float*)d_in[6], (const float*)d_in[10], (const float*)d_in[14]};
  const float* scw = (const float*)d_in[15];
  const float* scb = (const float*)d_in[16];
  const float* sbw = (const float*)d_in[17];
  const float* sbb = (const float*)d_in[18];
  const float* clsw = (const float*)d_in[19];
  const float* clsb = (const float*)d_in[20];
  const float* boxw = (const float*)d_in[21];
  const float* boxb = (const float*)d_in[22];
  const float* ctrw = (const float*)d_in[23];
  const float* ctrb = (const float*)d_in[24];
  float* out = (float*)d_out;
  u16* ws = (u16*)d_ws;

  size_t o = 0;
  auto alloc = [&](size_t n) { size_t r = o; o += (n + 127) & ~(size_t)127; return ws + r; };

  u16* c3t = alloc(524288);
  u16* c4t = alloc(327680);
  u16* c5t = alloc(204800);
  u16* l3 = alloc(2097152);
  u16* l4 = alloc(524288);
  u16* l5 = alloc(131072);
  u16* p3 = alloc(2097152);
  u16* p4 = alloc(524288);
  u16* p5 = alloc(131072);
  const size_t hsz[3] = {2097152, 524288, 131072};
  u16 *hc[2][3], *hb[2][3];
  for (int ab = 0; ab < 2; ++ab)
    for (int lvv = 0; lvv < 3; ++lvv) { hc[ab][lvv] = alloc(hsz[lvv]); hb[ab][lvv] = alloc(hsz[lvv]); }
  const int latCin[3] = {64, 160, 400};
  const int latNC[3] = {1, 3, 7};
  u16* wl[3]; for (int i = 0; i < 3; ++i) wl[i] = alloc((size_t)latNC[i] * 256 * 64);
  u16* wo[3]; for (int i = 0; i < 3; ++i) wo[i] = alloc(589824);
  u16* wsc[4]; for (int i = 0; i < 4; ++i) wsc[i] = alloc(589824);
  u16* wsb[4]; for (int i = 0; i < 4; ++i) wsb[i] = alloc(589824);
  u16* wcls = alloc(294912);
  u16* wbc = alloc(147456);
  float* bcls = (float*)alloc(256);
  float* bbc = (float*)alloc(128);

  // ---- weight transforms ----
  WArgs wa;
  int ji = 0;
  for (int i = 0; i < 3; ++i) wa.j[ji++] = WJob{lat_w[i], wl[i], latCin[i], 256, 1, latNC[i], 256, 0};
  for (int i = 0; i < 3; ++i) wa.j[ji++] = WJob{out_w[i], wo[i], 256, 256, 9, 4, 256, 0};
  for (int i = 0; i < 4; ++i) wa.j[ji++] = WJob{scw + (size_t)i * 589824, wsc[i], 256, 256, 9, 4, 256, 0};
  for (int i = 0; i < 4; ++i) wa.j[ji++] = WJob{sbw + (size_t)i * 589824, wsb[i], 256, 256, 9, 4, 256, 0};
  wa.j[ji++] = WJob{clsw, wcls, 256, 80, 9, 4, 128, 0};
  wa.j[ji++] = WJob{nullptr, wbc, 256, 5, 9, 4, 64, 1};
  wa.box_w = boxw; wa.ctr_w = ctrw;
  wa.cls_b = clsb; wa.box_b = boxb; wa.ctr_b = ctrb; wa.bcls = bcls; wa.bbc = bbc;
  wtrans_kernel<<<dim3(96, 16), dim3(256), 0, stream>>>(wa);

  // ---- f32 NCHW -> bf16 NHWC ----
  transpose_kernel<<<dim3(2048), dim3(256), 0, stream>>>(c3, c3t, 64, 4096, 524288);
  transpose_kernel<<<dim3(1280), dim3(256), 0, stream>>>(c4, c4t, 160, 1024, 327680);
  transpose_kernel<<<dim3(800), dim3(256), 0, stream>>>(c5, c5t, 400, 256, 204800);

  const int Hs[3] = {64, 32, 16};
  const int lgWs[3] = {6, 5, 4}, lgHWs[3] = {12, 10, 8};
  const int mt3[3] = {64, 16, 4};
  auto fillGeom = [&](ConvP& p, int i, int lvv, int taps) {
    p.H[i] = Hs[lvv]; p.W[i] = Hs[lvv]; p.lgW[i] = lgWs[lvv]; p.lgHW[i] = lgHWs[lvv];
    int tr = 128 >> lgWs[lvv];
    int hw2 = (taps == 9) ? Hs[lvv] + 2 : Hs[lvv];
    int hr = (taps == 9) ? tr + 2 : tr;
    p.haloW[i] = hw2; p.nA8[i] = hr * hw2 * 8;
  };

  // ---- lateral 1x1 convs (all levels fused) ----
  {
    ConvP p{};
    const u16* srcs[3] = {c3t, c4t, c5t};
    u16* dsts[3] = {l3, l4, l5};
    for (int i = 0; i < 3; ++i) {
      p.src[0][i] = srcs[i]; p.wT[0][i] = wl[i]; p.bias[0][i] = lat_b[i]; p.dst[0][i] = dsts[i];
      fillGeom(p, i, i, 1);
      p.NC[i] = latNC[i]; p.Crow[i] = latCin[i]; p.locoff[i] = 0;
    }
    p.pre[0] = 0; p.pre[1] = 64; p.pre[2] = 80;
    p.taps = 1; p.relu = 0; p.direct = 0; p.Nvalid = 0; p.choff = 0; p.CoutRow = 256; p.Cpad = 256;
    conv_kernel<<<dim3(84, 4, 1), dim3(256), 0, stream>>>(p);
  }

  // ---- FPN top-down ----
  auto out_conv = [&](int lvv, const u16* s, u16* dd) {
    ConvP p{};
    p.src[0][0] = s; p.wT[0][0] = wo[lvv]; p.bias[0][0] = out_b[lvv]; p.dst[0][0] = dd;
    fillGeom(p, 0, lvv, 9);
    p.NC[0] = 4; p.Crow[0] = 256; p.locoff[0] = 0;
    p.pre[0] = 0; p.pre[1] = 0x7fffffff; p.pre[2] = 0x7fffffff;
    p.taps = 9; p.relu = 0; p.direct = 0; p.Nvalid = 0; p.choff = 0; p.CoutRow = 256; p.Cpad = 256;
    conv_kernel<<<dim3(mt3[lvv], 4, 1), dim3(256), 0, stream>>>(p);
  };
  out_conv(2, l5, p5);
  upadd_kernel<<<dim3(2048), dim3(256), 0, stream>>>(l4, l5, 5, 10, 524288);
  out_conv(1, l4, p4);
  upadd_kernel<<<dim3(8192), dim3(256), 0, stream>>>(l3, l4, 6, 12, 2097152);
  out_conv(0, l3, p3);

  // ---- stem layers: all levels + both branches fused per layer ----
  u16* pin[3] = {p3, p4, p5};
  for (int i = 0; i < 4; ++i) {
    ConvP p{};
    int di = i & 1;
    for (int lvv = 0; lvv < 3; ++lvv) {
      const u16 *s0, *s1;
      if (i == 0) { s0 = pin[lvv]; s1 = pin[lvv]; }
      else { int si = (i - 1) & 1; s0 = hc[si][lvv]; s1 = hb[si][lvv]; }
      p.src[0][lvv] = s0; p.src[1][lvv] = s1;
      p.wT[0][lvv] = wsc[i]; p.wT[1][lvv] = wsb[i];
      p.bias[0][lvv] = scb + i * 256; p.bias[1][lvv] = sbb + i * 256;
      p.dst[0][lvv] = hc[di][lvv]; p.dst[1][lvv] = hb[di][lvv];
      fillGeom(p, lvv, lvv, 9);
      p.NC[lvv] = 4; p.Crow[lvv] = 256; p.locoff[lvv] = 0;
    }
    p.pre[0] = 0; p.pre[1] = 64; p.pre[2] = 80;
    p.taps = 9; p.relu = 1; p.direct = 0; p.Nvalid = 0; p.choff = 0; p.CoutRow = 256; p.Cpad = 256;
    conv_kernel<<<dim3(84, 4, 2), dim3(256), 0, stream>>>(p);
  }

  // ---- final cls / box+ctr convs, writing straight into f32 (B,5376,85) output ----
  const int locoffs[3] = {0, 4096, 5120};
  {
    ConvP p{};
    for (int lvv = 0; lvv < 3; ++lvv) {
      p.src[0][lvv] = hc[1][lvv]; p.wT[0][lvv] = wcls; p.bias[0][lvv] = bcls; p.dst[0][lvv] = out;
      fillGeom(p, lvv, lvv, 9);
      p.NC[lvv] = 4; p.Crow[lvv] = 256; p.locoff[lvv] = locoffs[lvv];
    }
    p.pre[0] = 0; p.pre[1] = 64; p.pre[2] = 80;
    p.taps = 9; p.relu = 0; p.direct = 1; p.Nvalid = 80; p.choff = 0; p.CoutRow = 256; p.Cpad = 128;
    conv_kernel<<<dim3(84, 2, 1), dim3(256), 0, stream>>>(p);
  }
  {
    ConvP p{};
    for (int lvv = 0; lvv < 3; ++lvv) {
      p.src[0][lvv] = hb[1][lvv]; p.wT[0][lvv] = wbc; p.bias[0][lvv] = bbc; p.dst[0][lvv] = out;
      fillGeom(p, lvv, lvv, 9);
      p.NC[lvv] = 4; p.Crow[lvv] = 256; p.locoff[lvv] = locoffs[lvv];
    }
    p.pre[0] = 0; p.pre[1] = 64; p.pre[2] = 80;
    p.taps = 9; p.relu = 0; p.direct = 1; p.Nvalid = 5; p.choff = 80; p.CoutRow = 256; p.Cpad = 64;
    conv_kernel<<<dim3(84, 1, 1), dim3(256), 0, stream>>>(p);
  }
}

// Round 4
// 512.126 us; speedup vs baseline: 1.6268x; 1.0745x over previous
//
#include <hip/hip_runtime.h>

typedef unsigned short u16;
typedef __attribute__((ext_vector_type(8))) __bf16 bf16x8;
typedef __attribute__((ext_vector_type(16))) float f32x16;

__device__ __forceinline__ float bf2f(u16 u) {
  union { unsigned i; float f; } x; x.i = ((unsigned)u) << 16; return x.f;
}
__device__ __forceinline__ u16 f2bf(float f) {
  union { float f; unsigned i; } x; x.f = f;
  unsigned r = x.i + 0x7FFFu + ((x.i >> 16) & 1u);
  return (u16)(r >> 16);
}
__device__ __forceinline__ bf16x8 as_bf(int4 v) {
  union { int4 i; bf16x8 b; } u; u.i = v; return u.b;
}

// ---------------- weight transform ----------------
// f32 w[Cout][Cin][3][3] -> bf16 wT[kk][n][64], kk = cc*taps + t (cc = 64-ch chunk)
struct WJob { const float* src; u16* dst; int Cin, Cout, taps, NC, Cpad, special; };
struct WArgs {
  WJob j[16];
  const float *box_w, *ctr_w;
  const float *cls_b, *box_b, *ctr_b;
  float *bcls, *bbc;
};

__global__ __launch_bounds__(256) void wtrans_kernel(WArgs a) {
  WJob jb = a.j[blockIdx.y];
  int count = jb.taps * jb.NC * jb.Cpad * 64;
  for (int e = blockIdx.x * 256 + threadIdx.x; e < count; e += gridDim.x * 256) {
    int cw = e & 63;
    int r = e >> 6;
    int n = r % jb.Cpad;
    int q = r / jb.Cpad;            // q = cc*taps + t
    int t = q % jb.taps;
    int cc = q / jb.taps;
    int ci = cc * 64 + cw;
    float v = 0.f;
    if (jb.special) {
      if (ci < jb.Cin) {
        if (n < 4) v = a.box_w[((size_t)n * jb.Cin + ci) * jb.taps + t];
        else if (n == 4) v = a.ctr_w[(size_t)ci * jb.taps + t];
      }
    } else if (n < jb.Cout && ci < jb.Cin) {
      v = jb.src[((size_t)n * jb.Cin + ci) * jb.taps + t];
    }
    jb.dst[e] = f2bf(v);
  }
  if (blockIdx.y == 0 && blockIdx.x == 0) {
    int t = threadIdx.x;
    if (t < 128) a.bcls[t] = (t < 80) ? a.cls_b[t] : 0.f;
    else if (t < 192) {
      int n = t - 128;
      a.bbc[n] = (n < 4) ? a.box_b[n] : (n == 4 ? a.ctr_b[0] : 0.f);
    }
  }
}

// ---------------- fused f32 NCHW -> bf16 NHWC (all 3 inputs) ----------------
__global__ __launch_bounds__(256) void transpose_kernel(const float* __restrict__ c3,
                                                        const float* __restrict__ c4,
                                                        const float* __restrict__ c5,
                                                        u16* __restrict__ c3t,
                                                        u16* __restrict__ c4t,
                                                        u16* __restrict__ c5t) {
  int gid = blockIdx.x * 256 + threadIdx.x;
  const float* in; u16* out; int C, HW;
  if (gid < 524288) { in = c3; out = c3t; C = 64; HW = 4096; }
  else if (gid < 851968) { gid -= 524288; in = c4; out = c4t; C = 160; HW = 1024; }
  else { gid -= 851968; if (gid >= 204800) return; in = c5; out = c5t; C = 400; HW = 256; }
  int CHW = C * HW;
  int b = gid / CHW;
  int rem = gid - b * CHW;
  int c = rem / HW;
  int pos = rem - c * HW;
  out[((size_t)b * HW + pos) * C + c] = f2bf(in[gid]);
}

// ---------------- fused upsample-adds ----------------
// l4n = l4 + up2(l5);  l3 += up2(l4) + up4(l5)   (composed nearest; race-free)
__global__ __launch_bounds__(256) void upadd2_kernel(u16* __restrict__ l3, u16* __restrict__ l4n,
                                                     const u16* __restrict__ l4,
                                                     const u16* __restrict__ l5) {
  int gid = blockIdx.x * 256 + threadIdx.x;
  if (gid < 524288) {
    int c = gid & 255; int m = gid >> 8;
    int b = m >> 10, pos = m & 1023;
    int y = pos >> 5, x = pos & 31;
    int sp = (b << 8) + ((y >> 1) << 4) + (x >> 1);
    l4n[gid] = f2bf(bf2f(l4[gid]) + bf2f(l5[(size_t)sp * 256 + c]));
  } else {
    int g2 = gid - 524288;
    int c = g2 & 255; int m = g2 >> 8;
    int b = m >> 12, pos = m & 4095;
    int y = pos >> 6, x = pos & 63;
    int sp2 = (b << 10) + ((y >> 1) << 5) + (x >> 1);
    int sp4 = (b << 8) + ((y >> 2) << 4) + (x >> 2);
    l3[g2] = f2bf(bf2f(l3[g2]) + bf2f(l4[(size_t)sp2 * 256 + c]) + bf2f(l5[(size_t)sp4 * 256 + c]));
  }
}

// ---------------- halo implicit-GEMM conv, register-pipelined ----------------
// BM=128 as a 16x8 patch, BN=64. A-halo (18x10) staged per 64-ch chunk from regs
// preloaded a full chunk earlier; B double-buffered in LDS, written from regs
// loaded 2 taps earlier. No barrier interval contains a dependent global load.
struct ConvP {
  const u16* src[2][3];
  const u16* wT[2][3];
  const float* bias[2][3];
  void* dst[2][3];
  int H[3], W[3], lgW[3], lgHW[3], pre[3], NC[3], Crow[3], locoff[3];
  int Cpad[2], Nvalid[2], choff[2], ny[2];
  int relu, direct, CoutRow;
};

#define APAD 72

template <int TAPS>
__global__ __launch_bounds__(256, 3) void conv_kernel(ConvP p) {
  constexpr int HALO_W = (TAPS == 9) ? 10 : 8;
  constexpr int HROWS = (TAPS == 9) ? 18 : 16;
  constexpr int NA = HROWS * HALO_W * 8;     // int4 staging units
  constexpr int NSLOT = (NA + 255) / 256;    // 6 or 4
  constexpr int OFF = (TAPS == 9) ? 1 : 0;
  __shared__ u16 As[180 * APAD];             // 25.9 KB
  __shared__ u16 Bs[2][64 * APAD];           // 18.4 KB
  const int tid = threadIdx.x;
  const int br = blockIdx.z;
  if (blockIdx.y >= p.ny[br]) return;
  const int bx = blockIdx.x;
  const int lv = (bx >= p.pre[1]) + (bx >= p.pre[2]);
  const u16* __restrict__ src = p.src[br][lv];
  const u16* __restrict__ wT = p.wT[br][lv];
  const float* bias = p.bias[br][lv];
  void* dstv = p.dst[br][lv];
  const int H = p.H[lv], W = p.W[lv];
  const int lgWv = p.lgW[lv], lgHWv = p.lgHW[lv];
  const int NCv = p.NC[lv], Crow = p.Crow[lv];
  const int Cpadv = p.Cpad[br];
  const int ktot = NCv * TAPS;
  const int nt = blockIdx.y * 64;
  const int wave = tid >> 6, lane = tid & 63;

  // patch decomposition
  const int pidx = bx - p.pre[lv];
  const int lgppb = lgHWv - 7;               // patches per batch (log2)
  const int lgnpx = lgWv - 3;                // patches per row (log2)
  const int batch = pidx >> lgppb;
  const int pp = pidx & ((1 << lgppb) - 1);
  const int py0 = (pp >> lgnpx) << 4;
  const int px0 = (pp & ((1 << lgnpx) - 1)) << 3;
  const size_t srcb = (size_t)batch * (1 << lgHWv) * Crow;

  f32x16 acc[2];
#pragma unroll
  for (int i = 0; i < 16; ++i) { acc[0][i] = 0.f; acc[1][i] = 0.f; }

  const int ml = wave * 32 + (lane & 31);
  const int my = ml >> 3, mx = ml & 7;
  const int koffs = (lane >> 5) << 3;        // shorts

  int4 rA[NSLOT];
  int4 rB[2][2];

  auto loadA = [&](int cc2, int4* r) {
    int kb = cc2 << 6;
#pragma unroll
    for (int s = 0; s < NSLOT; ++s) {
      int idx = s * 256 + tid;
      int4 v = make_int4(0, 0, 0, 0);
      if (idx < NA) {
        int pos = idx >> 3, part = idx & 7;
        int hy = pos / HALO_W, hx = pos - hy * HALO_W;
        int gy = py0 + hy - OFF, gx = px0 + hx - OFF;
        int ch = kb + (part << 3);
        if ((unsigned)gy < (unsigned)H && (unsigned)gx < (unsigned)W && ch < Crow)
          v = *(const int4*)(src + srcb + (size_t)((gy << lgWv) + gx) * Crow + ch);
      }
      r[s] = v;
    }
  };
  auto writeA = [&](const int4* r) {
#pragma unroll
    for (int s = 0; s < NSLOT; ++s) {
      int idx = s * 256 + tid;
      if (idx < NA) {
        int pos = idx >> 3, part = idx & 7;
        *(int4*)(As + pos * APAD + (part << 3)) = r[s];
      }
    }
  };
  auto loadB = [&](int j, int4* r) {
    const u16* wsrc = wT + (((size_t)j * Cpadv + nt) << 6);
    r[0] = *(const int4*)(wsrc + ((tid >> 3) << 6) + ((tid & 7) << 3));
    r[1] = *(const int4*)(wsrc + (((tid >> 3) + 32) << 6) + ((tid & 7) << 3));
  };
  auto writeB = [&](int bufi, const int4* r) {
    u16* bb = Bs[bufi];
    *(int4*)(bb + (tid >> 3) * APAD + ((tid & 7) << 3)) = r[0];
    *(int4*)(bb + ((tid >> 3) + 32) * APAD + ((tid & 7) << 3)) = r[1];
  };

  // prologue
  loadA(0, rA);
  loadB(0, rB[0]);
  if (ktot > 1) loadB(1, rB[1]);
  writeA(rA);
  writeB(0, rB[0]);
  if (ktot > 2) loadB(2, rB[0]);
  if (NCv > 1) loadA(1, rA);
  __syncthreads();

  for (int cc = 0; cc < NCv; ++cc) {
#pragma unroll
    for (int t = 0; t < TAPS; ++t) {
      const int kk = cc * TAPS + t;
      if (kk + 1 < ktot) {
        writeB((kk + 1) & 1, rB[(kk + 1) & 1]);
        if (kk + 3 < ktot) loadB(kk + 3, rB[(kk + 1) & 1]);
      }
      const int dy = (TAPS == 9) ? (t / 3 - 1) : 0;
      const int dx = (TAPS == 9) ? (t % 3 - 1) : 0;
      const int hp = (my + dy + OFF) * HALO_W + (mx + dx + OFF);
      const int4* ap = (const int4*)(As + hp * APAD + koffs);
      const int4* bp = (const int4*)(Bs[kk & 1] + (lane & 31) * APAD + koffs);
      const int4* bq = (const int4*)(Bs[kk & 1] + ((lane & 31) + 32) * APAD + koffs);
#pragma unroll
      for (int ks = 0; ks < 4; ++ks) {
        bf16x8 af = as_bf(ap[ks * 2]);
        acc[0] = __builtin_amdgcn_mfma_f32_32x32x16_bf16(af, as_bf(bp[ks * 2]), acc[0], 0, 0, 0);
        acc[1] = __builtin_amdgcn_mfma_f32_32x32x16_bf16(af, as_bf(bq[ks * 2]), acc[1], 0, 0, 0);
      }
      __syncthreads();
    }
    if (cc + 1 < NCv) {
      writeA(rA);
      if (cc + 2 < NCv) loadA(cc + 2, rA);
      __syncthreads();
    }
  }

  // epilogue: C/D layout col=lane&31, row=(reg&3)+8*(reg>>2)+4*(lane>>5)
  const int col = lane & 31;
  const int rb = 4 * (lane >> 5);
#pragma unroll
  for (int nf = 0; nf < 2; ++nf) {
    int n = nt + nf * 32 + col;
    float bv = bias[n];
#pragma unroll
    for (int r = 0; r < 16; ++r) {
      int m2 = wave * 32 + rb + (r & 3) + 8 * (r >> 2);
      int posi = ((py0 + (m2 >> 3)) << lgWv) + px0 + (m2 & 7);
      float v = acc[nf][r] + bv;
      if (p.relu) v = fmaxf(v, 0.f);
      if (!p.direct) {
        ((u16*)dstv)[((size_t)(batch << lgHWv) + posi) * p.CoutRow + n] = f2bf(v);
      } else {
        if (n < p.Nvalid[br]) {
          ((float*)dstv)[((size_t)(batch * 5376 + p.locoff[lv] + posi)) * 85 + p.choff[br] + n] = v;
        }
      }
    }
  }
}

// ---------------- host ----------------
extern "C" void kernel_launch(void* const* d_in, const int* in_sizes, int n_in,
                              void* d_out, int out_size, void* d_ws, size_t ws_size,
                              hipStream_t stream) {
  (void)in_sizes; (void)n_in; (void)out_size; (void)ws_size;
  const float* c3 = (const float*)d_in[0];
  const float* c4 = (const float*)d_in[1];
  const float* c5 = (const float*)d_in[2];
  const float* lat_w[3] = {(const float*)d_in[3], (const float*)d_in[7], (const float*)d_in[11]};
  const float* lat_b[3] = {(const float*)d_in[4], (const float*)d_in[8], (const float*)d_in[12]};
  const float* out_w[3] = {(const float*)d_in[5], (const float*)d_in[9], (const float*)d_in[13]};
  const float* out_b[3] = {(const float*)d_in[6], (const float*)d_in[10], (const float*)d_in[14]};
  const float* scw = (const float*)d_in[15];
  const float* scb = (const float*)d_in[16];
  const float* sbw = (const float*)d_in[17];
  const float* sbb = (const float*)d_in[18];
  const float* clsw = (const float*)d_in[19];
  const float* clsb = (const float*)d_in[20];
  const float* boxw = (const float*)d_in[21];
  const float* boxb = (const float*)d_in[22];
  const float* ctrw = (const float*)d_in[23];
  const float* ctrb = (const float*)d_in[24];
  float* out = (float*)d_out;
  u16* ws = (u16*)d_ws;

  size_t o = 0;
  auto alloc = [&](size_t n) { size_t r = o; o += (n + 127) & ~(size_t)127; return ws + r; };

  u16* c3t = alloc(524288);
  u16* c4t = alloc(327680);
  u16* c5t = alloc(204800);
  u16* l3 = alloc(2097152);
  u16* l4 = alloc(524288);
  u16* l4n = alloc(524288);
  u16* l5 = alloc(131072);
  u16* p3 = alloc(2097152);
  u16* p4 = alloc(524288);
  u16* p5 = alloc(131072);
  const size_t hsz[3] = {2097152, 524288, 131072};
  u16 *hc[2][3], *hb[2][3];
  for (int ab = 0; ab < 2; ++ab)
    for (int lvv = 0; lvv < 3; ++lvv) { hc[ab][lvv] = alloc(hsz[lvv]); hb[ab][lvv] = alloc(hsz[lvv]); }
  const int latCin[3] = {64, 160, 400};
  const int latNC[3] = {1, 3, 7};
  u16* wl[3]; for (int i = 0; i < 3; ++i) wl[i] = alloc((size_t)latNC[i] * 256 * 64);
  u16* wo[3]; for (int i = 0; i < 3; ++i) wo[i] = alloc(589824);
  u16* wsc[4]; for (int i = 0; i < 4; ++i) wsc[i] = alloc(589824);
  u16* wsb[4]; for (int i = 0; i < 4; ++i) wsb[i] = alloc(589824);
  u16* wcls = alloc(294912);
  u16* wbc = alloc(147456);
  float* bcls = (float*)alloc(256);
  float* bbc = (float*)alloc(128);

  // ---- weight transforms ----
  WArgs wa;
  int ji = 0;
  for (int i = 0; i < 3; ++i) wa.j[ji++] = WJob{lat_w[i], wl[i], latCin[i], 256, 1, latNC[i], 256, 0};
  for (int i = 0; i < 3; ++i) wa.j[ji++] = WJob{out_w[i], wo[i], 256, 256, 9, 4, 256, 0};
  for (int i = 0; i < 4; ++i) wa.j[ji++] = WJob{scw + (size_t)i * 589824, wsc[i], 256, 256, 9, 4, 256, 0};
  for (int i = 0; i < 4; ++i) wa.j[ji++] = WJob{sbw + (size_t)i * 589824, wsb[i], 256, 256, 9, 4, 256, 0};
  wa.j[ji++] = WJob{clsw, wcls, 256, 80, 9, 4, 128, 0};
  wa.j[ji++] = WJob{nullptr, wbc, 256, 5, 9, 4, 64, 1};
  wa.box_w = boxw; wa.ctr_w = ctrw;
  wa.cls_b = clsb; wa.box_b = boxb; wa.ctr_b = ctrb; wa.bcls = bcls; wa.bbc = bbc;
  wtrans_kernel<<<dim3(96, 16), dim3(256), 0, stream>>>(wa);

  // ---- f32 NCHW -> bf16 NHWC (fused) ----
  transpose_kernel<<<dim3(4128), dim3(256), 0, stream>>>(c3, c4, c5, c3t, c4t, c5t);

  const int Hs[3] = {64, 32, 16};
  const int lgWs[3] = {6, 5, 4}, lgHWs[3] = {12, 10, 8};

  auto setLv = [&](ConvP& p, int i, int lvv) {
    p.H[i] = Hs[lvv]; p.W[i] = Hs[lvv]; p.lgW[i] = lgWs[lvv]; p.lgHW[i] = lgHWs[lvv];
  };

  // ---- lateral 1x1 convs (all levels fused) ----
  {
    ConvP p{};
    const u16* srcs[3] = {c3t, c4t, c5t};
    u16* dsts[3] = {l3, l4, l5};
    for (int i = 0; i < 3; ++i) {
      p.src[0][i] = srcs[i]; p.wT[0][i] = wl[i]; p.bias[0][i] = lat_b[i]; p.dst[0][i] = dsts[i];
      setLv(p, i, i);
      p.NC[i] = latNC[i]; p.Crow[i] = latCin[i]; p.locoff[i] = 0;
    }
    p.pre[0] = 0; p.pre[1] = 64; p.pre[2] = 80;
    p.Cpad[0] = 256; p.Nvalid[0] = 0; p.choff[0] = 0; p.ny[0] = 4;
    p.relu = 0; p.direct = 0; p.CoutRow = 256;
    conv_kernel<1><<<dim3(84, 4, 1), dim3(256), 0, stream>>>(p);
  }

  // ---- fused upsample-adds: l4n = l4+up(l5); l3 += up(l4)+up4(l5) ----
  upadd2_kernel<<<dim3(10240), dim3(256), 0, stream>>>(l3, l4n, l4, l5);

  // ---- FPN out convs (all levels fused) ----
  {
    ConvP p{};
    const u16* srcs[3] = {l3, l4n, l5};
    u16* dsts[3] = {p3, p4, p5};
    for (int i = 0; i < 3; ++i) {
      p.src[0][i] = srcs[i]; p.wT[0][i] = wo[i]; p.bias[0][i] = out_b[i]; p.dst[0][i] = dsts[i];
      setLv(p, i, i);
      p.NC[i] = 4; p.Crow[i] = 256; p.locoff[i] = 0;
    }
    p.pre[0] = 0; p.pre[1] = 64; p.pre[2] = 80;
    p.Cpad[0] = 256; p.Nvalid[0] = 0; p.choff[0] = 0; p.ny[0] = 4;
    p.relu = 0; p.direct = 0; p.CoutRow = 256;
    conv_kernel<9><<<dim3(84, 4, 1), dim3(256), 0, stream>>>(p);
  }

  // ---- stem layers: all levels + both branches fused per layer ----
  u16* pin[3] = {p3, p4, p5};
  for (int i = 0; i < 4; ++i) {
    ConvP p{};
    int di = i & 1;
    for (int lvv = 0; lvv < 3; ++lvv) {
      const u16 *s0, *s1;
      if (i == 0) { s0 = pin[lvv]; s1 = pin[lvv]; }
      else { int si = (i - 1) & 1; s0 = hc[si][lvv]; s1 = hb[si][lvv]; }
      p.src[0][lvv] = s0; p.src[1][lvv] = s1;
      p.wT[0][lvv] = wsc[i]; p.wT[1][lvv] = wsb[i];
      p.bias[0][lvv] = scb + i * 256; p.bias[1][lvv] = sbb + i * 256;
      p.dst[0][lvv] = hc[di][lvv]; p.dst[1][lvv] = hb[di][lvv];
      setLv(p, lvv, lvv);
      p.NC[lvv] = 4; p.Crow[lvv] = 256; p.locoff[lvv] = 0;
    }
    p.pre[0] = 0; p.pre[1] = 64; p.pre[2] = 80;
    p.Cpad[0] = 256; p.Cpad[1] = 256;
    p.Nvalid[0] = 0; p.Nvalid[1] = 0; p.choff[0] = 0; p.choff[1] = 0;
    p.ny[0] = 4; p.ny[1] = 4;
    p.relu = 1; p.direct = 0; p.CoutRow = 256;
    conv_kernel<9><<<dim3(84, 4, 2), dim3(256), 0, stream>>>(p);
  }

  // ---- fused finals: z=0 cls (80ch), z=1 box+ctr (5ch), writing f32 (B,5376,85) ----
  {
    const int locoffs[3] = {0, 4096, 5120};
    ConvP p{};
    for (int lvv = 0; lvv < 3; ++lvv) {
      p.src[0][lvv] = hc[1][lvv]; p.wT[0][lvv] = wcls; p.bias[0][lvv] = bcls; p.dst[0][lvv] = out;
      p.src[1][lvv] = hb[1][lvv]; p.wT[1][lvv] = wbc; p.bias[1][lvv] = bbc; p.dst[1][lvv] = out;
      setLv(p, lvv, lvv);
      p.NC[lvv] = 4; p.Crow[lvv] = 256; p.locoff[lvv] = locoffs[lvv];
    }
    p.pre[0] = 0; p.pre[1] = 64; p.pre[2] = 80;
    p.Cpad[0] = 128; p.Cpad[1] = 64;
    p.Nvalid[0] = 80; p.Nvalid[1] = 5;
    p.choff[0] = 0; p.choff[1] = 80;
    p.ny[0] = 2; p.ny[1] = 1;
    p.relu = 0; p.direct = 1; p.CoutRow = 256;
    conv_kernel<9><<<dim3(84, 2, 2), dim3(256), 0, stream>>>(p);
  }
}

// Round 5
// 509.906 us; speedup vs baseline: 1.6339x; 1.0044x over previous
//
#include <hip/hip_runtime.h>

typedef unsigned short u16;
typedef __attribute__((ext_vector_type(8))) __bf16 bf16x8;
typedef __attribute__((ext_vector_type(16))) float f32x16;

__device__ __forceinline__ float bf2f(u16 u) {
  union { unsigned i; float f; } x; x.i = ((unsigned)u) << 16; return x.f;
}
__device__ __forceinline__ u16 f2bf(float f) {
  union { float f; unsigned i; } x; x.f = f;
  unsigned r = x.i + 0x7FFFu + ((x.i >> 16) & 1u);
  return (u16)(r >> 16);
}
__device__ __forceinline__ bf16x8 ld8(const u16* p) {
  union { int2 i2[2]; bf16x8 v; } u;
  u.i2[0] = *(const int2*)p;
  u.i2[1] = *(const int2*)(p + 4);
  return u.v;
}

// ---------------- weight transform ----------------
// f32 w[Cout][Cin][3][3] -> bf16 wT[kk][n][64], kk = cc*taps + t (cc = 64-ch chunk)
struct WJob { const float* src; u16* dst; int Cin, Cout, taps, NC, Cpad, special; };
struct WArgs {
  WJob j[16];
  const float *box_w, *ctr_w;
  const float *cls_b, *box_b, *ctr_b;
  float *bcls, *bbc;
};

__global__ __launch_bounds__(256) void wtrans_kernel(WArgs a) {
  WJob jb = a.j[blockIdx.y];
  int count = jb.taps * jb.NC * jb.Cpad * 64;
  for (int e = blockIdx.x * 256 + threadIdx.x; e < count; e += gridDim.x * 256) {
    int cw = e & 63;
    int r = e >> 6;
    int n = r % jb.Cpad;
    int q = r / jb.Cpad;            // q = cc*taps + t
    int t = q % jb.taps;
    int cc = q / jb.taps;
    int ci = cc * 64 + cw;
    float v = 0.f;
    if (jb.special) {
      if (ci < jb.Cin) {
        if (n < 4) v = a.box_w[((size_t)n * jb.Cin + ci) * jb.taps + t];
        else if (n == 4) v = a.ctr_w[(size_t)ci * jb.taps + t];
      }
    } else if (n < jb.Cout && ci < jb.Cin) {
      v = jb.src[((size_t)n * jb.Cin + ci) * jb.taps + t];
    }
    jb.dst[e] = f2bf(v);
  }
  if (blockIdx.y == 0 && blockIdx.x == 0) {
    int t = threadIdx.x;
    if (t < 128) a.bcls[t] = (t < 80) ? a.cls_b[t] : 0.f;
    else if (t < 192) {
      int n = t - 128;
      a.bbc[n] = (n < 4) ? a.box_b[n] : (n == 4 ? a.ctr_b[0] : 0.f);
    }
  }
}

// ---------------- fused f32 NCHW -> bf16 NHWC (all 3 inputs) ----------------
__global__ __launch_bounds__(256) void transpose_kernel(const float* __restrict__ c3,
                                                        const float* __restrict__ c4,
                                                        const float* __restrict__ c5,
                                                        u16* __restrict__ c3t,
                                                        u16* __restrict__ c4t,
                                                        u16* __restrict__ c5t) {
  int gid = blockIdx.x * 256 + threadIdx.x;
  const float* in; u16* out; int C, HW;
  if (gid < 524288) { in = c3; out = c3t; C = 64; HW = 4096; }
  else if (gid < 851968) { gid -= 524288; in = c4; out = c4t; C = 160; HW = 1024; }
  else { gid -= 851968; if (gid >= 204800) return; in = c5; out = c5t; C = 400; HW = 256; }
  int CHW = C * HW;
  int b = gid / CHW;
  int rem = gid - b * CHW;
  int c = rem / HW;
  int pos = rem - c * HW;
  out[((size_t)b * HW + pos) * C + c] = f2bf(in[gid]);
}

// ---------------- fused upsample-adds ----------------
// l4n = l4 + up2(l5);  l3 += up2(l4) + up4(l5)   (composed nearest; race-free)
__global__ __launch_bounds__(256) void upadd2_kernel(u16* __restrict__ l3, u16* __restrict__ l4n,
                                                     const u16* __restrict__ l4,
                                                     const u16* __restrict__ l5) {
  int gid = blockIdx.x * 256 + threadIdx.x;
  if (gid < 524288) {
    int c = gid & 255; int m = gid >> 8;
    int b = m >> 10, pos = m & 1023;
    int y = pos >> 5, x = pos & 31;
    int sp = (b << 8) + ((y >> 1) << 4) + (x >> 1);
    l4n[gid] = f2bf(bf2f(l4[gid]) + bf2f(l5[(size_t)sp * 256 + c]));
  } else {
    int g2 = gid - 524288;
    int c = g2 & 255; int m = g2 >> 8;
    int b = m >> 12, pos = m & 4095;
    int y = pos >> 6, x = pos & 63;
    int sp2 = (b << 10) + ((y >> 1) << 5) + (x >> 1);
    int sp4 = (b << 8) + ((y >> 2) << 4) + (x >> 2);
    l3[g2] = f2bf(bf2f(l3[g2]) + bf2f(l4[(size_t)sp2 * 256 + c]) + bf2f(l5[(size_t)sp4 * 256 + c]));
  }
}

// ---------------- halo implicit-GEMM conv, register-pipelined ----------------
// BM=128 as a 16x8 patch, BN=64. A-halo (18x10) staged per 64-ch chunk from regs
// preloaded a full chunk earlier; B double-buffered in LDS, written from regs
// loaded 2 taps earlier. APAD=68 (2-way-only bank aliasing, proven conflict-free).
struct ConvP {
  const u16* src[2][3];
  const u16* wT[2][3];
  const float* bias[2][3];
  void* dst[2][3];
  int H[3], W[3], lgW[3], lgHW[3], pre[3], NC[3], Crow[3], locoff[3];
  int Cpad[2], Nvalid[2], choff[2], ny[2];
  int relu, direct, CoutRow;
};

#define APAD 68

template <int TAPS>
__global__ __launch_bounds__(256, 3) void conv_kernel(ConvP p) {
  constexpr int HALO_W = (TAPS == 9) ? 10 : 8;
  constexpr int HROWS = (TAPS == 9) ? 18 : 16;
  constexpr int NA = HROWS * HALO_W * 8;     // int4 staging units
  constexpr int NSLOT = (NA + 255) / 256;    // 6 or 4
  constexpr int OFF = (TAPS == 9) ? 1 : 0;
  __shared__ u16 As[180 * APAD];             // 23.9 KB
  __shared__ u16 Bs[2][64 * APAD];           // 17.0 KB
  const int tid = threadIdx.x;
  const int br = blockIdx.z;
  if (blockIdx.y >= p.ny[br]) return;
  const int bx = blockIdx.x;
  const int lv = (bx >= p.pre[1]) + (bx >= p.pre[2]);
  const u16* __restrict__ src = p.src[br][lv];
  const u16* __restrict__ wT = p.wT[br][lv];
  const float* bias = p.bias[br][lv];
  void* dstv = p.dst[br][lv];
  const int H = p.H[lv], W = p.W[lv];
  const int lgWv = p.lgW[lv], lgHWv = p.lgHW[lv];
  const int NCv = p.NC[lv], Crow = p.Crow[lv];
  const int Cpadv = p.Cpad[br];
  const int ktot = NCv * TAPS;
  const int nt = blockIdx.y * 64;
  const int wave = tid >> 6, lane = tid & 63;

  // patch decomposition
  const int pidx = bx - p.pre[lv];
  const int lgppb = lgHWv - 7;               // patches per batch (log2)
  const int lgnpx = lgWv - 3;                // patches per row (log2)
  const int batch = pidx >> lgppb;
  const int pp = pidx & ((1 << lgppb) - 1);
  const int py0 = (pp >> lgnpx) << 4;
  const int px0 = (pp & ((1 << lgnpx) - 1)) << 3;
  const size_t srcb = (size_t)batch * (1 << lgHWv) * Crow;

  f32x16 acc[2];
#pragma unroll
  for (int i = 0; i < 16; ++i) { acc[0][i] = 0.f; acc[1][i] = 0.f; }

  const int ml = wave * 32 + (lane & 31);
  const int my = ml >> 3, mx = ml & 7;
  const int koffs = (lane >> 5) << 3;        // shorts

  int4 rA[NSLOT];
  int4 rB[2][2];

  auto loadA = [&](int cc2, int4* r) {
    int kb = cc2 << 6;
#pragma unroll
    for (int s = 0; s < NSLOT; ++s) {
      int idx = s * 256 + tid;
      int4 v = make_int4(0, 0, 0, 0);
      if (idx < NA) {
        int pos = idx >> 3, part = idx & 7;
        int hy = pos / HALO_W, hx = pos - hy * HALO_W;
        int gy = py0 + hy - OFF, gx = px0 + hx - OFF;
        int ch = kb + (part << 3);
        if ((unsigned)gy < (unsigned)H && (unsigned)gx < (unsigned)W && ch < Crow)
          v = *(const int4*)(src + srcb + (size_t)((gy << lgWv) + gx) * Crow + ch);
      }
      r[s] = v;
    }
  };
  auto writeA = [&](const int4* r) {
#pragma unroll
    for (int s = 0; s < NSLOT; ++s) {
      int idx = s * 256 + tid;
      if (idx < NA) {
        int pos = idx >> 3, part = idx & 7;
        u16* d = As + pos * APAD + (part << 3);
        *(int2*)d = make_int2(r[s].x, r[s].y);
        *(int2*)(d + 4) = make_int2(r[s].z, r[s].w);
      }
    }
  };
  auto loadB = [&](int j, int4* r) {
    const u16* wsrc = wT + (((size_t)j * Cpadv + nt) << 6);
    r[0] = *(const int4*)(wsrc + ((tid >> 3) << 6) + ((tid & 7) << 3));
    r[1] = *(const int4*)(wsrc + (((tid >> 3) + 32) << 6) + ((tid & 7) << 3));
  };
  auto writeB = [&](int bufi, const int4* r) {
    u16* bb = Bs[bufi];
    u16* d0 = bb + (tid >> 3) * APAD + ((tid & 7) << 3);
    u16* d1 = bb + ((tid >> 3) + 32) * APAD + ((tid & 7) << 3);
    *(int2*)d0 = make_int2(r[0].x, r[0].y);
    *(int2*)(d0 + 4) = make_int2(r[0].z, r[0].w);
    *(int2*)d1 = make_int2(r[1].x, r[1].y);
    *(int2*)(d1 + 4) = make_int2(r[1].z, r[1].w);
  };

  // prologue
  loadA(0, rA);
  loadB(0, rB[0]);
  if (ktot > 1) loadB(1, rB[1]);
  writeA(rA);
  writeB(0, rB[0]);
  if (ktot > 2) loadB(2, rB[0]);
  if (NCv > 1) loadA(1, rA);
  __syncthreads();

  for (int cc = 0; cc < NCv; ++cc) {
#pragma unroll
    for (int t = 0; t < TAPS; ++t) {
      const int kk = cc * TAPS + t;
      if (kk + 1 < ktot) {
        writeB((kk + 1) & 1, rB[(kk + 1) & 1]);
        if (kk + 3 < ktot) loadB(kk + 3, rB[(kk + 1) & 1]);
      }
      const int dy = (TAPS == 9) ? (t / 3 - 1) : 0;
      const int dx = (TAPS == 9) ? (t % 3 - 1) : 0;
      const int hp = (my + dy + OFF) * HALO_W + (mx + dx + OFF);
      const u16* ar = As + hp * APAD + koffs;
      const u16* br0 = Bs[kk & 1] + (lane & 31) * APAD + koffs;
      const u16* br1 = br0 + 32 * APAD;
#pragma unroll
      for (int ks = 0; ks < 4; ++ks) {
        bf16x8 af = ld8(ar + ks * 16);
        acc[0] = __builtin_amdgcn_mfma_f32_32x32x16_bf16(af, ld8(br0 + ks * 16), acc[0], 0, 0, 0);
        acc[1] = __builtin_amdgcn_mfma_f32_32x32x16_bf16(af, ld8(br1 + ks * 16), acc[1], 0, 0, 0);
      }
      __syncthreads();
    }
    if (cc + 1 < NCv) {
      writeA(rA);
      if (cc + 2 < NCv) loadA(cc + 2, rA);
      __syncthreads();
    }
  }

  // epilogue: C/D layout col=lane&31, row=(reg&3)+8*(reg>>2)+4*(lane>>5)
  // r-outer / nf-inner: each 128B output line completed by adjacent instructions
  const int col = lane & 31;
  const int rb = 4 * (lane >> 5);
  const float bv0 = bias[nt + col];
  const float bv1 = bias[nt + 32 + col];
#pragma unroll
  for (int r = 0; r < 16; ++r) {
    int m2 = wave * 32 + rb + (r & 3) + 8 * (r >> 2);
    int posi = ((py0 + (m2 >> 3)) << lgWv) + px0 + (m2 & 7);
    float v0 = acc[0][r] + bv0;
    float v1 = acc[1][r] + bv1;
    if (p.relu) { v0 = fmaxf(v0, 0.f); v1 = fmaxf(v1, 0.f); }
    if (!p.direct) {
      u16* dd = (u16*)dstv + ((size_t)(batch << lgHWv) + posi) * p.CoutRow + nt;
      dd[col] = f2bf(v0);
      dd[32 + col] = f2bf(v1);
    } else {
      float* dd = (float*)dstv + ((size_t)(batch * 5376 + p.locoff[lv] + posi)) * 85 + p.choff[br] + nt;
      int n0 = nt + col, n1 = nt + 32 + col;
      if (n0 < p.Nvalid[br]) dd[col] = v0;
      if (n1 < p.Nvalid[br]) dd[32 + col] = v1;
    }
  }
}

// ---------------- host ----------------
extern "C" void kernel_launch(void* const* d_in, const int* in_sizes, int n_in,
                              void* d_out, int out_size, void* d_ws, size_t ws_size,
                              hipStream_t stream) {
  (void)in_sizes; (void)n_in; (void)out_size; (void)ws_size;
  const float* c3 = (const float*)d_in[0];
  const float* c4 = (const float*)d_in[1];
  const float* c5 = (const float*)d_in[2];
  const float* lat_w[3] = {(const float*)d_in[3], (const float*)d_in[7], (const float*)d_in[11]};
  const float* lat_b[3] = {(const float*)d_in[4], (const float*)d_in[8], (const float*)d_in[12]};
  const float* out_w[3] = {(const float*)d_in[5], (const float*)d_in[9], (const float*)d_in[13]};
  const float* out_b[3] = {(const float*)d_in[6], (const float*)d_in[10], (const float*)d_in[14]};
  const float* scw = (const float*)d_in[15];
  const float* scb = (const float*)d_in[16];
  const float* sbw = (const float*)d_in[17];
  const float* sbb = (const float*)d_in[18];
  const float* clsw = (const float*)d_in[19];
  const float* clsb = (const float*)d_in[20];
  const float* boxw = (const float*)d_in[21];
  const float* boxb = (const float*)d_in[22];
  const float* ctrw = (const float*)d_in[23];
  const float* ctrb = (const float*)d_in[24];
  float* out = (float*)d_out;
  u16* ws = (u16*)d_ws;

  size_t o = 0;
  auto alloc = [&](size_t n) { size_t r = o; o += (n + 127) & ~(size_t)127; return ws + r; };

  u16* c3t = alloc(524288);
  u16* c4t = alloc(327680);
  u16* c5t = alloc(204800);
  u16* l3 = alloc(2097152);
  u16* l4 = alloc(524288);
  u16* l4n = alloc(524288);
  u16* l5 = alloc(131072);
  u16* p3 = alloc(2097152);
  u16* p4 = alloc(524288);
  u16* p5 = alloc(131072);
  const size_t hsz[3] = {2097152, 524288, 131072};
  u16 *hc[2][3], *hb[2][3];
  for (int ab = 0; ab < 2; ++ab)
    for (int lvv = 0; lvv < 3; ++lvv) { hc[ab][lvv] = alloc(hsz[lvv]); hb[ab][lvv] = alloc(hsz[lvv]); }
  const int latCin[3] = {64, 160, 400};
  const int latNC[3] = {1, 3, 7};
  u16* wl[3]; for (int i = 0; i < 3; ++i) wl[i] = alloc((size_t)latNC[i] * 256 * 64);
  u16* wo[3]; for (int i = 0; i < 3; ++i) wo[i] = alloc(589824);
  u16* wsc[4]; for (int i = 0; i < 4; ++i) wsc[i] = alloc(589824);
  u16* wsb[4]; for (int i = 0; i < 4; ++i) wsb[i] = alloc(589824);
  u16* wcls = alloc(294912);
  u16* wbc = alloc(147456);
  float* bcls = (float*)alloc(256);
  float* bbc = (float*)alloc(128);

  // ---- weight transforms ----
  WArgs wa;
  int ji = 0;
  for (int i = 0; i < 3; ++i) wa.j[ji++] = WJob{lat_w[i], wl[i], latCin[i], 256, 1, latNC[i], 256, 0};
  for (int i = 0; i < 3; ++i) wa.j[ji++] = WJob{out_w[i], wo[i], 256, 256, 9, 4, 256, 0};
  for (int i = 0; i < 4; ++i) wa.j[ji++] = WJob{scw + (size_t)i * 589824, wsc[i], 256, 256, 9, 4, 256, 0};
  for (int i = 0; i < 4; ++i) wa.j[ji++] = WJob{sbw + (size_t)i * 589824, wsb[i], 256, 256, 9, 4, 256, 0};
  wa.j[ji++] = WJob{clsw, wcls, 256, 80, 9, 4, 128, 0};
  wa.j[ji++] = WJob{nullptr, wbc, 256, 5, 9, 4, 64, 1};
  wa.box_w = boxw; wa.ctr_w = ctrw;
  wa.cls_b = clsb; wa.box_b = boxb; wa.ctr_b = ctrb; wa.bcls = bcls; wa.bbc = bbc;
  wtrans_kernel<<<dim3(96, 16), dim3(256), 0, stream>>>(wa);

  // ---- f32 NCHW -> bf16 NHWC (fused) ----
  transpose_kernel<<<dim3(4128), dim3(256), 0, stream>>>(c3, c4, c5, c3t, c4t, c5t);

  const int Hs[3] = {64, 32, 16};
  const int lgWs[3] = {6, 5, 4}, lgHWs[3] = {12, 10, 8};

  auto setLv = [&](ConvP& p, int i, int lvv) {
    p.H[i] = Hs[lvv]; p.W[i] = Hs[lvv]; p.lgW[i] = lgWs[lvv]; p.lgHW[i] = lgHWs[lvv];
  };

  // ---- lateral 1x1 convs (all levels fused) ----
  {
    ConvP p{};
    const u16* srcs[3] = {c3t, c4t, c5t};
    u16* dsts[3] = {l3, l4, l5};
    for (int i = 0; i < 3; ++i) {
      p.src[0][i] = srcs[i]; p.wT[0][i] = wl[i]; p.bias[0][i] = lat_b[i]; p.dst[0][i] = dsts[i];
      setLv(p, i, i);
      p.NC[i] = latNC[i]; p.Crow[i] = latCin[i]; p.locoff[i] = 0;
    }
    p.pre[0] = 0; p.pre[1] = 64; p.pre[2] = 80;
    p.Cpad[0] = 256; p.Nvalid[0] = 0; p.choff[0] = 0; p.ny[0] = 4;
    p.relu = 0; p.direct = 0; p.CoutRow = 256;
    conv_kernel<1><<<dim3(84, 4, 1), dim3(256), 0, stream>>>(p);
  }

  // ---- fused upsample-adds: l4n = l4+up(l5); l3 += up(l4)+up4(l5) ----
  upadd2_kernel<<<dim3(10240), dim3(256), 0, stream>>>(l3, l4n, l4, l5);

  // ---- FPN out convs (all levels fused) ----
  {
    ConvP p{};
    const u16* srcs[3] = {l3, l4n, l5};
    u16* dsts[3] = {p3, p4, p5};
    for (int i = 0; i < 3; ++i) {
      p.src[0][i] = srcs[i]; p.wT[0][i] = wo[i]; p.bias[0][i] = out_b[i]; p.dst[0][i] = dsts[i];
      setLv(p, i, i);
      p.NC[i] = 4; p.Crow[i] = 256; p.locoff[i] = 0;
    }
    p.pre[0] = 0; p.pre[1] = 64; p.pre[2] = 80;
    p.Cpad[0] = 256; p.Nvalid[0] = 0; p.choff[0] = 0; p.ny[0] = 4;
    p.relu = 0; p.direct = 0; p.CoutRow = 256;
    conv_kernel<9><<<dim3(84, 4, 1), dim3(256), 0, stream>>>(p);
  }

  // ---- stem layers: all levels + both branches fused per layer ----
  u16* pin[3] = {p3, p4, p5};
  for (int i = 0; i < 4; ++i) {
    ConvP p{};
    int di = i & 1;
    for (int lvv = 0; lvv < 3; ++lvv) {
      const u16 *s0, *s1;
      if (i == 0) { s0 = pin[lvv]; s1 = pin[lvv]; }
      else { int si = (i - 1) & 1; s0 = hc[si][lvv]; s1 = hb[si][lvv]; }
      p.src[0][lvv] = s0; p.src[1][lvv] = s1;
      p.wT[0][lvv] = wsc[i]; p.wT[1][lvv] = wsb[i];
      p.bias[0][lvv] = scb + i * 256; p.bias[1][lvv] = sbb + i * 256;
      p.dst[0][lvv] = hc[di][lvv]; p.dst[1][lvv] = hb[di][lvv];
      setLv(p, lvv, lvv);
      p.NC[lvv] = 4; p.Crow[lvv] = 256; p.locoff[lvv] = 0;
    }
    p.pre[0] = 0; p.pre[1] = 64; p.pre[2] = 80;
    p.Cpad[0] = 256; p.Cpad[1] = 256;
    p.Nvalid[0] = 0; p.Nvalid[1] = 0; p.choff[0] = 0; p.choff[1] = 0;
    p.ny[0] = 4; p.ny[1] = 4;
    p.relu = 1; p.direct = 0; p.CoutRow = 256;
    conv_kernel<9><<<dim3(84, 4, 2), dim3(256), 0, stream>>>(p);
  }

  // ---- fused finals: z=0 cls (80ch), z=1 box+ctr (5ch), writing f32 (B,5376,85) ----
  {
    const int locoffs[3] = {0, 4096, 5120};
    ConvP p{};
    for (int lvv = 0; lvv < 3; ++lvv) {
      p.src[0][lvv] = hc[1][lvv]; p.wT[0][lvv] = wcls; p.bias[0][lvv] = bcls; p.dst[0][lvv] = out;
      p.src[1][lvv] = hb[1][lvv]; p.wT[1][lvv] = wbc; p.bias[1][lvv] = bbc; p.dst[1][lvv] = out;
      setLv(p, lvv, lvv);
      p.NC[lvv] = 4; p.Crow[lvv] = 256; p.locoff[lvv] = locoffs[lvv];
    }
    p.pre[0] = 0; p.pre[1] = 64; p.pre[2] = 80;
    p.Cpad[0] = 128; p.Cpad[1] = 64;
    p.Nvalid[0] = 80; p.Nvalid[1] = 5;
    p.choff[0] = 0; p.choff[1] = 80;
    p.ny[0] = 2; p.ny[1] = 1;
    p.relu = 0; p.direct = 1; p.CoutRow = 256;
    conv_kernel<9><<<dim3(84, 2, 2), dim3(256), 0, stream>>>(p);
  }
}